// Round 1
// baseline (216.184 us; speedup 1.0000x reference)
//
#include <hip/hip_runtime.h>

// Problem: B=C=H=W=64, f32.
//   corr[b] = sum_chw map1[b]*map2[b];  corr /= ||corr||2;  corr = 1-corr;
//   out = map1 + map2 * corr[b]
//
// Geometry: per batch 64*64*64 = 262144 floats = 65536 float4.
//   32 blocks/batch x 256 threads x 8 float4/thread = 65536 float4. Exact.

#define THREADS 256
#define BLOCKS_PER_BATCH 32
#define VEC_PER_BATCH 65536   // 262144 / 4
#define VEC_PER_BLOCK 2048    // VEC_PER_BATCH / BLOCKS_PER_BATCH
#define VEC_PER_THREAD 8      // VEC_PER_BLOCK / THREADS
#define NBATCH 64

__global__ __launch_bounds__(THREADS) void corr_reduce_kernel(
    const float4* __restrict__ m1, const float4* __restrict__ m2,
    float* __restrict__ corr) {
  const int b = blockIdx.y;
  const int base = b * VEC_PER_BATCH + blockIdx.x * VEC_PER_BLOCK + threadIdx.x;

  float acc = 0.0f;
#pragma unroll
  for (int k = 0; k < VEC_PER_THREAD; ++k) {
    const float4 a = m1[base + k * THREADS];
    const float4 c = m2[base + k * THREADS];
    acc = fmaf(a.x, c.x, acc);
    acc = fmaf(a.y, c.y, acc);
    acc = fmaf(a.z, c.z, acc);
    acc = fmaf(a.w, c.w, acc);
  }

  // wave64 tree reduce
#pragma unroll
  for (int off = 32; off > 0; off >>= 1) acc += __shfl_down(acc, off);

  if ((threadIdx.x & 63) == 0) atomicAdd(&corr[b], acc);
}

__global__ __launch_bounds__(THREADS) void corr_apply_kernel(
    const float4* __restrict__ m1, const float4* __restrict__ m2,
    const float* __restrict__ corr, float4* __restrict__ out) {
  __shared__ float c_sh;
  const int b = blockIdx.y;

  // Wave 0 recomputes the L2 norm of the 64-element corr vector (cheap,
  // L2-cached) and derives this batch's scalar.
  if (threadIdx.x < 64) {
    const float v = corr[threadIdx.x];
    float sq = v * v;
#pragma unroll
    for (int off = 32; off > 0; off >>= 1) sq += __shfl_down(sq, off);
    if (threadIdx.x == 0) c_sh = 1.0f - corr[b] * rsqrtf(sq);
  }
  __syncthreads();
  const float c = c_sh;

  const int base = b * VEC_PER_BATCH + blockIdx.x * VEC_PER_BLOCK + threadIdx.x;
#pragma unroll
  for (int k = 0; k < VEC_PER_THREAD; ++k) {
    const float4 a = m1[base + k * THREADS];
    const float4 v = m2[base + k * THREADS];
    float4 o;
    o.x = fmaf(v.x, c, a.x);
    o.y = fmaf(v.y, c, a.y);
    o.z = fmaf(v.z, c, a.z);
    o.w = fmaf(v.w, c, a.w);
    out[base + k * THREADS] = o;
  }
}

extern "C" void kernel_launch(void* const* d_in, const int* in_sizes, int n_in,
                              void* d_out, int out_size, void* d_ws, size_t ws_size,
                              hipStream_t stream) {
  const float4* m1 = (const float4*)d_in[0];
  const float4* m2 = (const float4*)d_in[1];
  float* corr = (float*)d_ws;           // 64 floats of scratch
  float4* out = (float4*)d_out;

  // d_ws is poisoned to 0xAA before every launch — zero the accumulators.
  hipMemsetAsync(corr, 0, NBATCH * sizeof(float), stream);

  dim3 grid(BLOCKS_PER_BATCH, NBATCH);
  corr_reduce_kernel<<<grid, THREADS, 0, stream>>>(m1, m2, corr);
  corr_apply_kernel<<<grid, THREADS, 0, stream>>>(m1, m2, corr, out);
}

// Round 2
// 186.479 us; speedup vs baseline: 1.1593x; 1.1593x over previous
//
#include <hip/hip_runtime.h>

// B=C=H=W=64, f32.
//   corr[b] = sum_chw map1[b]*map2[b];  corr /= ||corr||;  c = 1-corr;
//   out = map1 + map2 * c[b]
//
// Per batch: 262144 floats = 65536 float4. 32 blocks/batch x 256 thr x
// 8 float4/thread. Kernel 1 writes one partial per block (64*32 = 2048
// floats in d_ws, no atomics, no memset). Kernel 2 redundantly reduces the
// 8 KB of partials per block (cache-hit) while its first 8 streaming loads
// are in flight, then applies out = fma(m2, c, m1).

#define THREADS 256
#define BPB 32            // blocks per batch
#define VPB 65536         // float4 per batch
#define VPBLK 2048        // float4 per block
#define NBATCH 64

__global__ __launch_bounds__(THREADS, 8) void corr_reduce_kernel(
    const float4* __restrict__ m1, const float4* __restrict__ m2,
    float* __restrict__ partials) {
  const int b = blockIdx.y;
  const int base = b * VPB + blockIdx.x * VPBLK + threadIdx.x;

  float acc = 0.0f;
#pragma unroll
  for (int r = 0; r < 2; ++r) {
    const int o = base + r * 4 * THREADS;
    // stage 8 loads before any use -> deep MLP within the 64-VGPR cap
    const float4 a0 = m1[o];
    const float4 a1 = m1[o + THREADS];
    const float4 a2 = m1[o + 2 * THREADS];
    const float4 a3 = m1[o + 3 * THREADS];
    const float4 c0 = m2[o];
    const float4 c1 = m2[o + THREADS];
    const float4 c2 = m2[o + 2 * THREADS];
    const float4 c3 = m2[o + 3 * THREADS];
    acc = fmaf(a0.x, c0.x, acc); acc = fmaf(a0.y, c0.y, acc);
    acc = fmaf(a0.z, c0.z, acc); acc = fmaf(a0.w, c0.w, acc);
    acc = fmaf(a1.x, c1.x, acc); acc = fmaf(a1.y, c1.y, acc);
    acc = fmaf(a1.z, c1.z, acc); acc = fmaf(a1.w, c1.w, acc);
    acc = fmaf(a2.x, c2.x, acc); acc = fmaf(a2.y, c2.y, acc);
    acc = fmaf(a2.z, c2.z, acc); acc = fmaf(a2.w, c2.w, acc);
    acc = fmaf(a3.x, c3.x, acc); acc = fmaf(a3.y, c3.y, acc);
    acc = fmaf(a3.z, c3.z, acc); acc = fmaf(a3.w, c3.w, acc);
  }

  // wave64 butterfly reduce
#pragma unroll
  for (int off = 32; off > 0; off >>= 1) acc += __shfl_xor(acc, off);

  __shared__ float wsum[4];
  const int wave = threadIdx.x >> 6;
  if ((threadIdx.x & 63) == 0) wsum[wave] = acc;
  __syncthreads();
  if (threadIdx.x == 0)
    partials[b * BPB + blockIdx.x] = wsum[0] + wsum[1] + wsum[2] + wsum[3];
}

__global__ __launch_bounds__(THREADS, 8) void corr_apply_kernel(
    const float4* __restrict__ m1, const float4* __restrict__ m2,
    const float* __restrict__ partials, float4* __restrict__ out) {
  const int b = blockIdx.y;
  const int base = b * VPB + blockIdx.x * VPBLK + threadIdx.x;

  // Issue first half of the streaming loads BEFORE the corr computation so
  // the scalar prelude hides under HBM latency.
  const float4 a0 = m1[base];
  const float4 a1 = m1[base + THREADS];
  const float4 a2 = m1[base + 2 * THREADS];
  const float4 a3 = m1[base + 3 * THREADS];
  const float4 v0 = m2[base];
  const float4 v1 = m2[base + THREADS];
  const float4 v2 = m2[base + 2 * THREADS];
  const float4 v3 = m2[base + 3 * THREADS];

  __shared__ float c_sh;
  if (threadIdx.x < 64) {
    float s = 0.0f;
#pragma unroll
    for (int i = 0; i < BPB; ++i) s += partials[threadIdx.x * BPB + i];
    float sq = s * s;
#pragma unroll
    for (int off = 32; off > 0; off >>= 1) sq += __shfl_xor(sq, off);
    const float cb = __shfl(s, b);           // corr[b] lives in lane b
    if (threadIdx.x == 0) c_sh = 1.0f - cb * rsqrtf(sq);
  }
  __syncthreads();
  const float c = c_sh;

  float4 o;
  o.x = fmaf(v0.x, c, a0.x); o.y = fmaf(v0.y, c, a0.y);
  o.z = fmaf(v0.z, c, a0.z); o.w = fmaf(v0.w, c, a0.w);
  out[base] = o;
  o.x = fmaf(v1.x, c, a1.x); o.y = fmaf(v1.y, c, a1.y);
  o.z = fmaf(v1.z, c, a1.z); o.w = fmaf(v1.w, c, a1.w);
  out[base + THREADS] = o;
  o.x = fmaf(v2.x, c, a2.x); o.y = fmaf(v2.y, c, a2.y);
  o.z = fmaf(v2.z, c, a2.z); o.w = fmaf(v2.w, c, a2.w);
  out[base + 2 * THREADS] = o;
  o.x = fmaf(v3.x, c, a3.x); o.y = fmaf(v3.y, c, a3.y);
  o.z = fmaf(v3.z, c, a3.z); o.w = fmaf(v3.w, c, a3.w);
  out[base + 3 * THREADS] = o;

  // second half
  const int base2 = base + 4 * THREADS;
  const float4 b0 = m1[base2];
  const float4 b1 = m1[base2 + THREADS];
  const float4 b2 = m1[base2 + 2 * THREADS];
  const float4 b3 = m1[base2 + 3 * THREADS];
  const float4 w0 = m2[base2];
  const float4 w1 = m2[base2 + THREADS];
  const float4 w2 = m2[base2 + 2 * THREADS];
  const float4 w3 = m2[base2 + 3 * THREADS];

  o.x = fmaf(w0.x, c, b0.x); o.y = fmaf(w0.y, c, b0.y);
  o.z = fmaf(w0.z, c, b0.z); o.w = fmaf(w0.w, c, b0.w);
  out[base2] = o;
  o.x = fmaf(w1.x, c, b1.x); o.y = fmaf(w1.y, c, b1.y);
  o.z = fmaf(w1.z, c, b1.z); o.w = fmaf(w1.w, c, b1.w);
  out[base2 + THREADS] = o;
  o.x = fmaf(w2.x, c, b2.x); o.y = fmaf(w2.y, c, b2.y);
  o.z = fmaf(w2.z, c, b2.z); o.w = fmaf(w2.w, c, b2.w);
  out[base2 + 2 * THREADS] = o;
  o.x = fmaf(w3.x, c, b3.x); o.y = fmaf(w3.y, c, b3.y);
  o.z = fmaf(w3.z, c, b3.z); o.w = fmaf(w3.w, c, b3.w);
  out[base2 + 3 * THREADS] = o;
}

extern "C" void kernel_launch(void* const* d_in, const int* in_sizes, int n_in,
                              void* d_out, int out_size, void* d_ws, size_t ws_size,
                              hipStream_t stream) {
  const float4* m1 = (const float4*)d_in[0];
  const float4* m2 = (const float4*)d_in[1];
  float* partials = (float*)d_ws;        // 2048 floats (8 KB) of scratch
  float4* out = (float4*)d_out;

  dim3 grid(BPB, NBATCH);
  corr_reduce_kernel<<<grid, THREADS, 0, stream>>>(m1, m2, partials);
  corr_apply_kernel<<<grid, THREADS, 0, stream>>>(m1, m2, partials, out);
}

// Round 3
// 183.988 us; speedup vs baseline: 1.1750x; 1.0135x over previous
//
#include <hip/hip_runtime.h>

// B=C=H=W=64, f32.
//   corr[b] = sum_chw map1[b]*map2[b];  corr /= ||corr||;  c = 1-corr;
//   out = map1 + map2 * c[b]
//
// Round 3: force-staged loads (arrays + sched_barrier) for deep memory-level
// parallelism. Round-2 evidence: 48 us regardless of L3-hot/cold => the
// kernel was latency/concurrency-bound (VGPR=32 -> ~2 outstanding loads),
// not BW-bound.
//
// Geometry: 65536 float4 per batch. grid(64,64): 64 blocks/batch x 256 thr
// x 4 float4/thread. partials[64 batches][64 blocks] = 4096 floats in d_ws.

#define THREADS 256
#define NBATCH 64
#define BPB 64                // blocks per batch
#define V4B 65536             // float4 per batch
#define V4BLK 1024            // float4 per block

__global__ __launch_bounds__(THREADS, 8) void corr_reduce_kernel(
    const float4* __restrict__ m1, const float4* __restrict__ m2,
    float* __restrict__ partials) {
  const int b = blockIdx.y;
  const int base = b * V4B + blockIdx.x * V4BLK + threadIdx.x;

  float4 a[4], v[4];
#pragma unroll
  for (int k = 0; k < 4; ++k) a[k] = m1[base + k * THREADS];
#pragma unroll
  for (int k = 0; k < 4; ++k) v[k] = m2[base + k * THREADS];
  __builtin_amdgcn_sched_barrier(0);   // all 8 loads issued before any use

  float acc0 = 0.f, acc1 = 0.f, acc2 = 0.f, acc3 = 0.f;
#pragma unroll
  for (int k = 0; k < 4; ++k) {
    acc0 = fmaf(a[k].x, v[k].x, acc0);
    acc1 = fmaf(a[k].y, v[k].y, acc1);
    acc2 = fmaf(a[k].z, v[k].z, acc2);
    acc3 = fmaf(a[k].w, v[k].w, acc3);
  }
  float acc = (acc0 + acc1) + (acc2 + acc3);

#pragma unroll
  for (int off = 32; off > 0; off >>= 1) acc += __shfl_xor(acc, off);

  __shared__ float wsum[4];
  if ((threadIdx.x & 63) == 0) wsum[threadIdx.x >> 6] = acc;
  __syncthreads();
  if (threadIdx.x == 0)
    partials[b * BPB + blockIdx.x] = (wsum[0] + wsum[1]) + (wsum[2] + wsum[3]);
}

__global__ __launch_bounds__(THREADS, 4) void corr_apply_kernel(
    const float4* __restrict__ m1, const float4* __restrict__ m2,
    const float4* __restrict__ partials4, float4* __restrict__ out) {
  const int b = blockIdx.y;
  const int base = b * V4B + blockIdx.x * V4BLK + threadIdx.x;

  // streaming loads first...
  float4 a[4], v[4];
#pragma unroll
  for (int k = 0; k < 4; ++k) a[k] = m1[base + k * THREADS];
#pragma unroll
  for (int k = 0; k < 4; ++k) v[k] = m2[base + k * THREADS];

  // ...plus the corr prelude loads, all in flight before the joint drain.
  // 4096 partial floats = 1024 float4; thread t sums floats [16t, 16t+16),
  // which all belong to batch t/4.
  float4 p[4];
#pragma unroll
  for (int k = 0; k < 4; ++k) p[k] = partials4[threadIdx.x * 4 + k];
  __builtin_amdgcn_sched_barrier(0);

  float s = 0.f;
#pragma unroll
  for (int k = 0; k < 4; ++k) s += (p[k].x + p[k].y) + (p[k].z + p[k].w);
  s += __shfl_xor(s, 1);
  s += __shfl_xor(s, 2);               // corr[t/4], replicated in 4-lane group

  __shared__ float csh[NBATCH];
  __shared__ float c_sh;
  if ((threadIdx.x & 3) == 0) csh[threadIdx.x >> 2] = s;
  __syncthreads();
  if (threadIdx.x < 64) {
    float cv = csh[threadIdx.x];
    float sq = cv * cv;
#pragma unroll
    for (int off = 32; off > 0; off >>= 1) sq += __shfl_xor(sq, off);
    if (threadIdx.x == 0) c_sh = 1.0f - csh[b] * rsqrtf(sq);
  }
  __syncthreads();
  const float c = c_sh;

#pragma unroll
  for (int k = 0; k < 4; ++k) {
    float4 o;
    o.x = fmaf(v[k].x, c, a[k].x);
    o.y = fmaf(v[k].y, c, a[k].y);
    o.z = fmaf(v[k].z, c, a[k].z);
    o.w = fmaf(v[k].w, c, a[k].w);
    out[base + k * THREADS] = o;
  }
}

extern "C" void kernel_launch(void* const* d_in, const int* in_sizes, int n_in,
                              void* d_out, int out_size, void* d_ws, size_t ws_size,
                              hipStream_t stream) {
  const float4* m1 = (const float4*)d_in[0];
  const float4* m2 = (const float4*)d_in[1];
  float* partials = (float*)d_ws;          // 4096 floats (16 KB) scratch
  float4* out = (float4*)d_out;

  dim3 grid(BPB, NBATCH);
  corr_reduce_kernel<<<grid, THREADS, 0, stream>>>(m1, m2, partials);
  corr_apply_kernel<<<grid, THREADS, 0, stream>>>(m1, m2, (const float4*)partials, out);
}